// Round 1
// baseline (700.807 us; speedup 1.0000x reference)
//
#include <hip/hip_runtime.h>
#include <math.h>

#define BB   4
#define HH   96
#define WW   96
#define HW   (HH * WW)     // 9216
#define CIN  64
#define COUT 64
#define KK9  9
#define CIN2 130           // 64 + 64 + 2

// ---------------------------------------------------------------------------
// Kernel A: 3x3 convs producing offset (18 ch) and modulator (9 ch) from
// concat(frame_i, frame_j, flow). Thread = (b, y, x, group g) where group g
// computes combined output channels 3g, 3g+1, 3g+2 (0..17 = offset, 18..26 =
// modulator). Lanes run along x -> coalesced input loads. Weight indices are
// wave-uniform (readfirstlane) -> scalar loads.
// ---------------------------------------------------------------------------
__global__ __launch_bounds__(256) void conv_offmod_kernel(
    const float* __restrict__ fi, const float* __restrict__ fj,
    const float* __restrict__ fl, const float* __restrict__ w_off,
    const float* __restrict__ b_off, const float* __restrict__ w_mod,
    const float* __restrict__ b_mod, float* __restrict__ off_out,
    float* __restrict__ mod_out)
{
    int gid = blockIdx.x * blockDim.x + threadIdx.x;   // 9 * 4 * 9216 threads
    int x  = gid % WW;
    int y  = (gid / WW) % HH;
    int gb = gid / HW;                 // uniform per wave (HW % 64 == 0)
    gb = __builtin_amdgcn_readfirstlane(gb);
    int b = gb & 3;                    // 0..3
    int g = gb >> 2;                   // 0..8

    // combined output channels for this thread
    int oc0 = 3 * g;                   // 0..24 step 3; never straddles 18
    bool is_mod = (oc0 >= 18);

    const float* wbase[3];
    float acc[3];
#pragma unroll
    for (int j = 0; j < 3; ++j) {
        int oc = oc0 + j;
        if (oc < 18) {
            wbase[j] = w_off + oc * (CIN2 * KK9);
            acc[j] = b_off[oc];
        } else {
            wbase[j] = w_mod + (oc - 18) * (CIN2 * KK9);
            acc[j] = b_mod[oc - 18];
        }
    }

    // validity flags for the 3x3 patch (zero padding)
    bool ym = (y - 1 >= 0), yp = (y + 1 < HH);
    bool xm = (x - 1 >= 0), xp = (x + 1 < WW);
    bool okt[9] = { ym && xm, ym, ym && xp,
                    xm,       true, xp,
                    yp && xm, yp, yp && xp };
    int  idxt[9];
#pragma unroll
    for (int t = 0; t < 9; ++t) {
        int yy = y + t / 3 - 1;
        int xx = x + t % 3 - 1;
        yy = min(max(yy, 0), HH - 1);
        xx = min(max(xx, 0), WW - 1);
        idxt[t] = yy * WW + xx;
    }

    for (int ci = 0; ci < CIN2; ++ci) {
        const float* plane;
        if (ci < 64)       plane = fi + (size_t)(b * 64 + ci) * HW;
        else if (ci < 128) plane = fj + (size_t)(b * 64 + (ci - 64)) * HW;
        else               plane = fl + (size_t)(b * 2 + (ci - 128)) * HW;

        float p[9];
#pragma unroll
        for (int t = 0; t < 9; ++t)
            p[t] = okt[t] ? plane[idxt[t]] : 0.0f;

#pragma unroll
        for (int j = 0; j < 3; ++j) {
            const float* wr = wbase[j] + ci * KK9;
#pragma unroll
            for (int t = 0; t < 9; ++t)
                acc[j] = fmaf(p[t], wr[t], acc[j]);
        }
    }

    int hw = y * WW + x;
#pragma unroll
    for (int j = 0; j < 3; ++j) {
        int oc = oc0 + j;
        if (!is_mod) {
            off_out[((size_t)(b * 18 + oc)) * HW + hw] = acc[j];
        } else {
            float m = 2.0f / (1.0f + expf(-acc[j]));
            mod_out[((size_t)(b * 9 + (oc - 18))) * HW + hw] = m;
        }
    }
}

// ---------------------------------------------------------------------------
// Kernel B: modulated deformable conv. Thread = (b, og, y, x) where og selects
// 8 output channels o = og*8 + j. Each thread gathers each bilinear sample
// once (per c,k) and reuses it for its 8 accumulators. Weight reads are
// wave-uniform -> scalar loads. Lanes run along x -> coalesced gathers/stores.
// ---------------------------------------------------------------------------
__global__ __launch_bounds__(256) void deform_kernel(
    const float* __restrict__ fj, const float* __restrict__ off_in,
    const float* __restrict__ mod_in, const float* __restrict__ w_reg,
    float* __restrict__ out)
{
    int gid = blockIdx.x * blockDim.x + threadIdx.x;   // 4 * 8 * 9216 threads
    int x  = gid % WW;
    int y  = (gid / WW) % HH;
    int c2 = gid / HW;                 // uniform per wave
    c2 = __builtin_amdgcn_readfirstlane(c2);
    int og = c2 & 7;                   // 0..7
    int b  = c2 >> 3;                  // 0..3
    int hw = y * WW + x;

    const float* offp = off_in + (size_t)b * 18 * HW + hw;
    const float* modp = mod_in + (size_t)b * 9 * HW + hw;
    const float* img  = fj + (size_t)b * CIN * HW;
    const float* wr0  = w_reg + (size_t)(og * 8) * (CIN * KK9);  // [o][c][k]

    float acc[8] = {0.f, 0.f, 0.f, 0.f, 0.f, 0.f, 0.f, 0.f};

    for (int k = 0; k < KK9; ++k) {
        int ky = k / 3, kx = k % 3;
        float dy = offp[(size_t)(2 * k) * HW];
        float dx = offp[(size_t)(2 * k + 1) * HW];
        float m  = modp[(size_t)k * HW];

        float py = (float)(y - 1 + ky) + dy;
        float px = (float)(x - 1 + kx) + dx;
        float fy = floorf(py), fx = floorf(px);
        int   y0 = (int)fy,    x0 = (int)fx;
        float wy = py - fy,    wx = px - fx;
        int   y1 = y0 + 1,     x1 = x0 + 1;

        bool y0v = (y0 >= 0) && (y0 < HH);
        bool y1v = (y1 >= 0) && (y1 < HH);
        bool x0v = (x0 >= 0) && (x0 < WW);
        bool x1v = (x1 >= 0) && (x1 < WW);

        float w00 = (1.f - wy) * (1.f - wx) * ((y0v && x0v) ? m : 0.f);
        float w01 = (1.f - wy) * wx         * ((y0v && x1v) ? m : 0.f);
        float w10 = wy * (1.f - wx)         * ((y1v && x0v) ? m : 0.f);
        float w11 = wy * wx                 * ((y1v && x1v) ? m : 0.f);

        int y0c = min(max(y0, 0), HH - 1), y1c = min(max(y1, 0), HH - 1);
        int x0c = min(max(x0, 0), WW - 1), x1c = min(max(x1, 0), WW - 1);
        int i00 = y0c * WW + x0c;
        int i01 = y0c * WW + x1c;
        int i10 = y1c * WW + x0c;
        int i11 = y1c * WW + x1c;

        const float* wk = wr0 + k;     // advance by 9 per c, 576 per j
        const float* pl = img;
        for (int c = 0; c < CIN; ++c) {
            float v = w00 * pl[i00] + w01 * pl[i01]
                    + w10 * pl[i10] + w11 * pl[i11];
#pragma unroll
            for (int j = 0; j < 8; ++j)
                acc[j] = fmaf(v, wk[(size_t)j * (CIN * KK9)], acc[j]);
            pl += HW;
            wk += KK9;
        }
    }

#pragma unroll
    for (int j = 0; j < 8; ++j) {
        int o = og * 8 + j;
        out[((size_t)(b * COUT + o)) * HW + hw] = acc[j];
    }
}

extern "C" void kernel_launch(void* const* d_in, const int* in_sizes, int n_in,
                              void* d_out, int out_size, void* d_ws, size_t ws_size,
                              hipStream_t stream)
{
    const float* frame_i = (const float*)d_in[0];
    const float* frame_j = (const float*)d_in[1];
    const float* flow_ij = (const float*)d_in[2];
    const float* w_off   = (const float*)d_in[3];
    const float* b_off   = (const float*)d_in[4];
    const float* w_mod   = (const float*)d_in[5];
    const float* b_mod   = (const float*)d_in[6];
    const float* w_reg   = (const float*)d_in[7];
    float* out = (float*)d_out;

    float* ws_off = (float*)d_ws;                       // [4,18,96,96]
    float* ws_mod = ws_off + (size_t)BB * 18 * HW;      // [4,9,96,96]

    // Kernel A: 9 groups * 4 batches * 9216 positions = 331776 threads
    {
        int total = 9 * BB * HW;
        int block = 256;
        int grid  = total / block;
        conv_offmod_kernel<<<grid, block, 0, stream>>>(
            frame_i, frame_j, flow_ij, w_off, b_off, w_mod, b_mod,
            ws_off, ws_mod);
    }

    // Kernel B: 8 ogroups * 4 batches * 9216 positions = 294912 threads
    {
        int total = 8 * BB * HW;
        int block = 256;
        int grid  = total / block;
        deform_kernel<<<grid, block, 0, stream>>>(
            frame_j, ws_off, ws_mod, w_reg, out);
    }
}

// Round 2
// 455.528 us; speedup vs baseline: 1.5384x; 1.5384x over previous
//
#include <hip/hip_runtime.h>
#include <math.h>

#define BB   4
#define HH   96
#define WW   96
#define HW   (HH * WW)          // 9216
#define CIN  64
#define COUT 64
#define C2P  132                // concat channels 130 padded to 132
#define NROW (BB * HW)          // 36864
#define ZROW NROW               // extra all-zero row for invalid conv taps

typedef float f4 __attribute__((ext_vector_type(4)));

__device__ __forceinline__ f4 fma4s(float s, f4 w, f4 a) {
    a.x = fmaf(s, w.x, a.x);
    a.y = fmaf(s, w.y, a.y);
    a.z = fmaf(s, w.z, a.z);
    a.w = fmaf(s, w.w, a.w);
    return a;
}

// ---------------------------------------------------------------------------
// Pre-pass 1: Xt[b*HW + hw][132] = concat(fi[64], fj[64], flow[2], 0, 0).
// Row ZROW (=NROW) is all zeros (conv border taps redirect here).
// Reads coalesced (lanes along hw); writes 16B scattered (L2 absorbs).
// ---------------------------------------------------------------------------
__global__ __launch_bounds__(256) void transpose_x_kernel(
    const float* __restrict__ fi, const float* __restrict__ fj,
    const float* __restrict__ fl, float* __restrict__ xt)
{
    int r = blockIdx.x * 256 + threadIdx.x;
    if (r > NROW) return;
    float* dst = xt + (size_t)r * C2P;
    if (r == NROW) {
        for (int c = 0; c < C2P; ++c) dst[c] = 0.0f;
        return;
    }
    int b = r / HW, hw = r % HW;
    const float* pi = fi + (size_t)b * CIN * HW + hw;
    const float* pj = fj + (size_t)b * CIN * HW + hw;
    const float* pf = fl + (size_t)b * 2 * HW + hw;
    f4 v;
#pragma unroll 4
    for (int cq = 0; cq < 16; ++cq) {
        v.x = pi[(size_t)(4 * cq + 0) * HW];
        v.y = pi[(size_t)(4 * cq + 1) * HW];
        v.z = pi[(size_t)(4 * cq + 2) * HW];
        v.w = pi[(size_t)(4 * cq + 3) * HW];
        *(f4*)(dst + 4 * cq) = v;
    }
#pragma unroll 4
    for (int cq = 0; cq < 16; ++cq) {
        v.x = pj[(size_t)(4 * cq + 0) * HW];
        v.y = pj[(size_t)(4 * cq + 1) * HW];
        v.z = pj[(size_t)(4 * cq + 2) * HW];
        v.w = pj[(size_t)(4 * cq + 3) * HW];
        *(f4*)(dst + 64 + 4 * cq) = v;
    }
    v.x = pf[0];
    v.y = pf[HW];
    v.z = 0.0f;
    v.w = 0.0f;
    *(f4*)(dst + 128) = v;
}

// ---------------------------------------------------------------------------
// Pre-pass 2: weight transposes.
// Wa[(t*132 + c)*36 + g*12 + j]  (t=tap, c=concat channel, g=out group 0..2,
//   j=0..8 -> combined out channel 9g+j; j=9..11 and c>=130 are zero pad)
// Wb[(k*64 + c)*64 + o] = w_reg[o][c][k]
// ---------------------------------------------------------------------------
__global__ __launch_bounds__(256) void transpose_w_kernel(
    const float* __restrict__ w_off, const float* __restrict__ w_mod,
    const float* __restrict__ w_reg, float* __restrict__ wa,
    float* __restrict__ wb)
{
    int e = blockIdx.x * 256 + threadIdx.x;
    const int NA = 9 * 132 * 36;
    if (e < NA) {
        int j = e % 12;
        int g = (e / 12) % 3;
        int c = (e / 36) % 132;
        int t = e / (36 * 132);
        float v = 0.0f;
        if (j < 9 && c < 130) {
            int oc = g * 9 + j;
            if (oc < 18) v = w_off[((size_t)oc * 130 + c) * 9 + t];
            else         v = w_mod[((size_t)(oc - 18) * 130 + c) * 9 + t];
        }
        wa[e] = v;
    } else {
        int e2 = e - NA;
        if (e2 < 9 * 64 * 64) {
            int o = e2 % 64;
            int c = (e2 / 64) % 64;
            int k = e2 / 4096;
            wb[e2] = w_reg[((size_t)o * 64 + c) * 9 + k];
        }
    }
}

// ---------------------------------------------------------------------------
// Kernel A: offset+modulator 3x3 convs. Thread = (b, g, hw), g in {0,1,2}
// computes 9 combined outputs (g=0,1: offset ch 9g..9g+8; g=2: mod ch 0..8).
// Input patch rows read as float4 from Xt; invalid taps -> zero row.
// Weights are wave-uniform -> scalar loads.
// ---------------------------------------------------------------------------
__global__ __launch_bounds__(256) void conv_offmod_kernel(
    const float* __restrict__ xt, const float* __restrict__ wa,
    const float* __restrict__ b_off, const float* __restrict__ b_mod,
    float* __restrict__ off_out, float* __restrict__ mod_out)
{
    int gid = blockIdx.x * 256 + threadIdx.x;   // 3*4*9216 threads
    int hw = gid % HW;
    int c2 = __builtin_amdgcn_readfirstlane(gid / HW);  // 0..11 uniform
    int b = c2 & 3;
    int g = c2 >> 2;                            // 0..2
    int x = hw % WW, y = hw / WW;

    float acc[9];
#pragma unroll
    for (int j = 0; j < 9; ++j)
        acc[j] = (g < 2) ? b_off[g * 9 + j] : b_mod[j];

    bool ym = y > 0, yp = y < HH - 1, xm = x > 0, xp = x < WW - 1;
    bool okt[9] = { ym && xm, ym, ym && xp,
                    xm,       true, xp,
                    yp && xm, yp, yp && xp };
    int rbase = b * HW;
    int rows[9];
#pragma unroll
    for (int t = 0; t < 9; ++t) {
        int yy = y + t / 3 - 1;
        int xx = x + t % 3 - 1;
        int idx = rbase + yy * WW + xx;         // garbage when invalid; unused
        rows[t] = okt[t] ? idx : ZROW;
    }

#pragma unroll
    for (int t = 0; t < 9; ++t) {
        const f4* xp4 = (const f4*)(xt + (size_t)rows[t] * C2P);
        const float* wt = wa + (size_t)t * 132 * 36 + g * 12;
#pragma unroll 3
        for (int cq = 0; cq < 33; ++cq) {
            f4 xv = xp4[cq];
#pragma unroll
            for (int cc = 0; cc < 4; ++cc) {
                float xs = (cc == 0) ? xv.x : (cc == 1) ? xv.y
                         : (cc == 2) ? xv.z : xv.w;
                const float* wr = wt + (size_t)(4 * cq + cc) * 36;
#pragma unroll
                for (int j = 0; j < 9; ++j)
                    acc[j] = fmaf(xs, wr[j], acc[j]);
            }
        }
    }

    if (g < 2) {
#pragma unroll
        for (int j = 0; j < 9; ++j)
            off_out[((size_t)(b * 18 + g * 9 + j)) * HW + hw] = acc[j];
    } else {
#pragma unroll
        for (int j = 0; j < 9; ++j)
            mod_out[((size_t)(b * 9 + j)) * HW + hw] =
                2.0f / (1.0f + expf(-acc[j]));
    }
}

// ---------------------------------------------------------------------------
// Kernel B: modulated deformable conv. Thread = (b, og, hw), og in {0..3}
// computes 16 outputs o = 16*og + j. Per (k, c-quad): 4 float4 gathers from
// Xt (fj channels at +64), bilinear combine, 64 FMAs into 4 f4 accumulators.
// Invalid taps get zero bilinear weight (clamped addresses still loaded).
// ---------------------------------------------------------------------------
__global__ __launch_bounds__(256) void deform_kernel(
    const float* __restrict__ xt, const float* __restrict__ wb,
    const float* __restrict__ off_in, const float* __restrict__ mod_in,
    float* __restrict__ out)
{
    int gid = blockIdx.x * 256 + threadIdx.x;   // 4*4*9216 threads
    int hw = gid % HW;
    int c2 = __builtin_amdgcn_readfirstlane(gid / HW);  // 0..15 uniform
    int og = c2 & 3;
    int b  = c2 >> 2;
    int x = hw % WW, y = hw / WW;

    const float* offp = off_in + (size_t)b * 18 * HW + hw;
    const float* modp = mod_in + (size_t)b * 9 * HW + hw;

    f4 acc0 = {0.f, 0.f, 0.f, 0.f};
    f4 acc1 = acc0, acc2 = acc0, acc3 = acc0;

    for (int k = 0; k < 9; ++k) {
        int ky = k / 3, kx = k - 3 * ky;
        float dy = offp[(size_t)(2 * k) * HW];
        float dx = offp[(size_t)(2 * k + 1) * HW];
        float m  = modp[(size_t)k * HW];

        float py = (float)(y - 1 + ky) + dy;
        float px = (float)(x - 1 + kx) + dx;
        float fy = floorf(py), fx = floorf(px);
        int   y0 = (int)fy,    x0 = (int)fx;
        float wy = py - fy,    wx = px - fx;
        int   y1 = y0 + 1,     x1 = x0 + 1;

        bool y0v = (y0 >= 0) && (y0 < HH);
        bool y1v = (y1 >= 0) && (y1 < HH);
        bool x0v = (x0 >= 0) && (x0 < WW);
        bool x1v = (x1 >= 0) && (x1 < WW);

        float w00 = (1.f - wy) * (1.f - wx) * ((y0v && x0v) ? m : 0.f);
        float w01 = (1.f - wy) * wx         * ((y0v && x1v) ? m : 0.f);
        float w10 = wy * (1.f - wx)         * ((y1v && x0v) ? m : 0.f);
        float w11 = wy * wx                 * ((y1v && x1v) ? m : 0.f);

        int y0c = min(max(y0, 0), HH - 1), y1c = min(max(y1, 0), HH - 1);
        int x0c = min(max(x0, 0), WW - 1), x1c = min(max(x1, 0), WW - 1);
        int rb = b * HW;
        const f4* p00 = (const f4*)(xt + (size_t)(rb + y0c * WW + x0c) * C2P + 64);
        const f4* p01 = (const f4*)(xt + (size_t)(rb + y0c * WW + x1c) * C2P + 64);
        const f4* p10 = (const f4*)(xt + (size_t)(rb + y1c * WW + x0c) * C2P + 64);
        const f4* p11 = (const f4*)(xt + (size_t)(rb + y1c * WW + x1c) * C2P + 64);

        const float* wk = wb + (size_t)k * 64 * 64 + og * 16;
#pragma unroll 2
        for (int cq = 0; cq < 16; ++cq) {
            f4 a00 = p00[cq], a01 = p01[cq], a10 = p10[cq], a11 = p11[cq];
            f4 v;
            v.x = fmaf(w11, a11.x, fmaf(w10, a10.x, fmaf(w01, a01.x, w00 * a00.x)));
            v.y = fmaf(w11, a11.y, fmaf(w10, a10.y, fmaf(w01, a01.y, w00 * a00.y)));
            v.z = fmaf(w11, a11.z, fmaf(w10, a10.z, fmaf(w01, a01.z, w00 * a00.z)));
            v.w = fmaf(w11, a11.w, fmaf(w10, a10.w, fmaf(w01, a01.w, w00 * a00.w)));
#pragma unroll
            for (int cc = 0; cc < 4; ++cc) {
                float vs = (cc == 0) ? v.x : (cc == 1) ? v.y
                         : (cc == 2) ? v.z : v.w;
                const f4* wv = (const f4*)(wk + (size_t)(4 * cq + cc) * 64);
                acc0 = fma4s(vs, wv[0], acc0);
                acc1 = fma4s(vs, wv[1], acc1);
                acc2 = fma4s(vs, wv[2], acc2);
                acc3 = fma4s(vs, wv[3], acc3);
            }
        }
    }

    float* op = out + ((size_t)(b * COUT + og * 16)) * HW + hw;
    op[(size_t)0  * HW] = acc0.x;  op[(size_t)1  * HW] = acc0.y;
    op[(size_t)2  * HW] = acc0.z;  op[(size_t)3  * HW] = acc0.w;
    op[(size_t)4  * HW] = acc1.x;  op[(size_t)5  * HW] = acc1.y;
    op[(size_t)6  * HW] = acc1.z;  op[(size_t)7  * HW] = acc1.w;
    op[(size_t)8  * HW] = acc2.x;  op[(size_t)9  * HW] = acc2.y;
    op[(size_t)10 * HW] = acc2.z;  op[(size_t)11 * HW] = acc2.w;
    op[(size_t)12 * HW] = acc3.x;  op[(size_t)13 * HW] = acc3.y;
    op[(size_t)14 * HW] = acc3.z;  op[(size_t)15 * HW] = acc3.w;
}

extern "C" void kernel_launch(void* const* d_in, const int* in_sizes, int n_in,
                              void* d_out, int out_size, void* d_ws, size_t ws_size,
                              hipStream_t stream)
{
    const float* frame_i = (const float*)d_in[0];
    const float* frame_j = (const float*)d_in[1];
    const float* flow_ij = (const float*)d_in[2];
    const float* w_off   = (const float*)d_in[3];
    const float* b_off   = (const float*)d_in[4];
    const float* w_mod   = (const float*)d_in[5];
    const float* b_mod   = (const float*)d_in[6];
    const float* w_reg   = (const float*)d_in[7];
    float* out = (float*)d_out;

    // workspace layout (floats): Xt | Wa | Wb | off | mod  (~23.8 MB total)
    float* xt  = (float*)d_ws;
    float* wa  = xt  + (size_t)(NROW + 1) * C2P;      // 4,866,180
    float* wb  = wa  + 9 * 132 * 36;                  // 42,768
    float* off = wb  + 9 * 64 * 64;                   // 36,864
    float* mod = off + (size_t)BB * 18 * HW;          // 663,552
    //           mod: BB*9*HW = 331,776

    {   // transposes (independent, cheap)
        int rows = NROW + 1;
        transpose_x_kernel<<<(rows + 255) / 256, 256, 0, stream>>>(
            frame_i, frame_j, flow_ij, xt);
        int wtotal = 9 * 132 * 36 + 9 * 64 * 64;
        transpose_w_kernel<<<(wtotal + 255) / 256, 256, 0, stream>>>(
            w_off, w_mod, w_reg, wa, wb);
    }

    {   // conv: 3 groups * 4 batches * 9216 positions = 110592 threads
        int total = 3 * BB * HW;
        conv_offmod_kernel<<<total / 256, 256, 0, stream>>>(
            xt, wa, b_off, b_mod, off, mod);
    }

    {   // deform: 4 ogroups * 4 batches * 9216 positions = 147456 threads
        int total = 4 * BB * HW;
        deform_kernel<<<total / 256, 256, 0, stream>>>(
            xt, wb, off, mod, out);
    }
}